// Round 10
// baseline (3087.964 us; speedup 1.0000x reference)
//
#include <hip/hip_runtime.h>

#define B_ 64
#define S_ 512
#define D_ 256
#define H_ 512

typedef __attribute__((ext_vector_type(8))) short bfx8;
typedef __attribute__((ext_vector_type(4))) float f32x4;

#define MFMA16(a,b,c) __builtin_amdgcn_mfma_f32_16x16x32_bf16((a),(b),(c),0,0,0)
#define AL(p) __hip_atomic_load((p), __ATOMIC_RELAXED, __HIP_MEMORY_SCOPE_AGENT)

__device__ __forceinline__ unsigned short f2bf(float x){
  union { float f; unsigned int u; } v; v.f = x;
  unsigned int r = v.u + 0x7fffu + ((v.u >> 16) & 1u);
  return (unsigned short)(r >> 16);
}
__device__ __forceinline__ float bf2f(unsigned short b){
  union { unsigned int u; float f; } v; v.u = ((unsigned int)b) << 16; return v.f;
}
__device__ __forceinline__ float sigm(float x){ return 1.f/(1.f + __expf(-x)); }
__device__ __forceinline__ float tanhfast(float x){
  float xc = fminf(fmaxf(x, -15.f), 15.f);
  float e = __expf(2.f * xc);
  return (e - 1.f) / (e + 1.f);
}
// sc0 load: bypass L1, served by local XCD L2 (or LLC on miss)
__device__ __forceinline__ unsigned int ld_sc0_u32(const int* p){
  unsigned int r;
  asm volatile("global_load_dword %0, %1, off sc0\n\ts_waitcnt vmcnt(0)"
               : "=v"(r) : "v"(p) : "memory");
  return r;
}
__device__ __forceinline__ void unpack8(uint4 a, uint4 b, bfx8& hi, bfx8& lo){
  hi[0]=(short)(a.x>>16); lo[0]=(short)(a.x&0xffffu);
  hi[1]=(short)(a.y>>16); lo[1]=(short)(a.y&0xffffu);
  hi[2]=(short)(a.z>>16); lo[2]=(short)(a.z&0xffffu);
  hi[3]=(short)(a.w>>16); lo[3]=(short)(a.w&0xffffu);
  hi[4]=(short)(b.x>>16); lo[4]=(short)(b.x&0xffffu);
  hi[5]=(short)(b.y>>16); lo[5]=(short)(b.y&0xffffu);
  hi[6]=(short)(b.z>>16); lo[6]=(short)(b.z&0xffffu);
  hi[7]=(short)(b.w>>16); lo[7]=(short)(b.w&0xffffu);
}
__device__ __forceinline__ void cvt8(const float* vv, bfx8& hi, bfx8& lo){
  #pragma unroll
  for (int j = 0; j < 8; ++j) {
    unsigned short h = f2bf(vv[j]);
    hi[j] = (short)h;
    lo[j] = (short)f2bf(vv[j] - bf2f(h));
  }
}

// ---------------- prep: x fragments [t][q][kt(8)][lane(64)][8] hi/lo ----------------
__global__ void __launch_bounds__(256) k_xfrag(const float* __restrict__ x,
                                               unsigned short* __restrict__ xhi,
                                               unsigned short* __restrict__ xlo){
  int idx = blockIdx.x*256 + threadIdx.x;            // 2^20 threads
  int lane = idx & 63, kt = (idx>>6)&7, q = (idx>>9)&3, t = idx>>11;
  int b = q*16 + (lane&15);
  int k0 = kt*32 + ((lane>>4)&3)*8;
  const float4* p = (const float4*)(x + ((size_t)b*S_ + t)*D_ + k0);
  float4 v0 = p[0], v1 = p[1];
  float vv[8] = {v0.x,v0.y,v0.z,v0.w,v1.x,v1.y,v1.z,v1.w};
  bfx8 hi, lo; cvt8(vv, hi, lo);
  *(bfx8*)(xhi + (size_t)idx*8) = hi;
  *(bfx8*)(xlo + (size_t)idx*8) = lo;
}

// ---------------- prep: Wih fragments [dir][q][r(32)][kt(8)][nt(4)][lane(64)][8] ----------------
__global__ void __launch_bounds__(256) k_wfrag(const float* __restrict__ fWih,
                                               const float* __restrict__ bWih,
                                               unsigned short* __restrict__ whi,
                                               unsigned short* __restrict__ wlo){
  int idx = blockIdx.x*256 + threadIdx.x;            // 2^19 threads
  int lane = idx & 63, nt = (idx>>6)&3, kt = (idx>>8)&7, r = (idx>>11)&31, dir = (idx>>18)&1;
  int row = nt*512 + r*16 + (lane&15);
  int k0 = kt*32 + ((lane>>4)&3)*8;
  const float* W = dir ? bWih : fWih;
  const float4* p = (const float4*)(W + (size_t)row*D_ + k0);
  float4 v0 = p[0], v1 = p[1];
  float vv[8] = {v0.x,v0.y,v0.z,v0.w,v1.x,v1.y,v1.z,v1.w};
  bfx8 hi, lo; cvt8(vv, hi, lo);
  *(bfx8*)(whi + (size_t)idx*8) = hi;
  *(bfx8*)(wlo + (size_t)idx*8) = lo;
}

// ---------------- prep: att_W fragments [nt(4)][kt(32)][lane(64)][8] ----------------
__global__ void __launch_bounds__(256) k_awfrag(const float* __restrict__ attW,
                                                unsigned short* __restrict__ awhi,
                                                unsigned short* __restrict__ awlo){
  int idx = blockIdx.x*256 + threadIdx.x;            // 8192 threads
  int lane = idx & 63, kt = (idx>>6)&31, nt = idx>>11;
  int n = nt*16 + (lane&15);
  int k0 = kt*32 + ((lane>>4)&3)*8;
  const float4* p = (const float4*)(attW + (size_t)n*1024 + k0);
  float4 v0 = p[0], v1 = p[1];
  float vv[8] = {v0.x,v0.y,v0.z,v0.w,v1.x,v1.y,v1.z,v1.w};
  bfx8 hi, lo; cvt8(vv, hi, lo);
  *(bfx8*)(awhi + (size_t)idx*8) = hi;
  *(bfx8*)(awlo + (size_t)idx*8) = lo;
}

// ---------------- main recurrence: 256 WGs = 8 groups(dir x quarter) x 32 col-WGs ----------------
// DUAL-PATH exchange: producers store h and the digest TWICE to the same address with the
// same value -- one plain store (dirty in the local XCD L2: fast path for the XCD-local
// group, ~200cy RTT) + one agent-atomic store (LLC: correctness for any dispatch mapping).
// Consumers: bulk read = plain uint4 loads (addresses read once -> L1 never stale; L1-miss
// hits local L2). Digest poll = sc0 loads (bypass L1, read L2) with every-32nd-iteration
// escalation to an agent-atomic LLC load as the cross-XCD progress guarantee.
__global__ void __launch_bounds__(256,1) k_lstm(
    const float* __restrict__ fWhh, const float* __restrict__ bWhh,
    const float* __restrict__ fbih, const float* __restrict__ fbhh,
    const float* __restrict__ bbih, const float* __restrict__ bbhh,
    unsigned int* __restrict__ hpk,
    const unsigned short* __restrict__ xhi, const unsigned short* __restrict__ xlo,
    const unsigned short* __restrict__ whi, const unsigned short* __restrict__ wlo,
    int* __restrict__ dg)
{
  extern __shared__ char smem[];
  unsigned short* shh   = (unsigned short*)smem;            // Whh hi frags kt0..13 = 57344 B
  unsigned short* shl   = shh + 28672;                      // Whh lo frags kt0..13 = 57344 B
  unsigned short* sh_hi = (unsigned short*)(smem + 114688); // staged h hi [kt16][lane64][8] = 16 KB
  unsigned short* sh_lo = sh_hi + 8192;                     // staged h lo = 16 KB
  float* gbuf = (float*)(smem + 147456);                    // dedicated gate exchange [4][16][16] = 4 KB

  const int tid = threadIdx.x, bid = blockIdx.x;
  const int g = bid & 7, r = bid >> 3;                      // bid&7: round-robin dispatch -> group likely XCD-local
  const int dir = g >> 2, q = g & 3;
  const int wv = tid >> 6, lane = tid & 63;
  const float* Whh = dir ? bWhh : fWhh;

  // stage Whh slice: kt 0..13 -> LDS fragments; kt 14,15 -> registers (exact per-thread match)
  bfx8 rbh0, rbl0, rbh1, rbl1;
  #pragma unroll
  for (int i = 0; i < 16; ++i) {
    int fl = tid & 63, fnt = (tid>>6)&3;
    int row = fnt*512 + r*16 + (fl&15);
    int k0 = i*32 + ((fl>>4)&3)*8;
    const float4* p = (const float4*)(Whh + (size_t)row*H_ + k0);
    float4 v0 = p[0], v1 = p[1];
    float vv[8] = {v0.x,v0.y,v0.z,v0.w,v1.x,v1.y,v1.z,v1.w};
    bfx8 hi, lo; cvt8(vv, hi, lo);
    if (i < 14) {
      *(bfx8*)(shh + (size_t)((i*4+fnt)*64+fl)*8) = hi;
      *(bfx8*)(shl + (size_t)((i*4+fnt)*64+fl)*8) = lo;
    } else if (i == 14) { rbh0 = hi; rbl0 = lo; }
    else                { rbh1 = hi; rbl1 = lo; }
  }

  // Wih fragments -> registers (constant across steps)
  bfx8 wrh[8], wrl[8];
  {
    const size_t wb = (((size_t)(dir*4+q)*32 + r)*32 + wv)*64;
    #pragma unroll
    for (int kt = 0; kt < 8; ++kt) {
      wrh[kt] = *(const bfx8*)(whi + (wb + kt*256 + lane)*8);
      wrl[kt] = *(const bfx8*)(wlo + (wb + kt*256 + lane)*8);
    }
  }

  const int b_l = tid >> 4, cc = tid & 15;
  const int jcol = r*16 + cc;
  const float* bih = dir ? bbih : fbih;
  const float* bhh = dir ? bbhh : fbhh;
  float bias[4];
  #pragma unroll
  for (int gt = 0; gt < 4; ++gt) bias[gt] = bih[gt*512 + jcol] + bhh[gt*512 + jcol];
  float cst = 0.f;
  const int hkt   = jcol >> 5;
  const int hlane = ((jcol>>3)&3)*16 + b_l;
  const int hj    = jcol & 7;
  const int dgi   = g*32 + (lane & 31);     // each lane polls one producer's epoch word
  const int kts   = tid >> 7;               // 0: even kts, 1: odd kts
  const int tl    = tid & 127;              // 128-thread subgroup index
  __syncthreads();

  for (int ti = 0; ti < S_; ++ti) {
    const int t = dir ? (S_-1-ti) : ti;
    f32x4 a0 = {0.f,0.f,0.f,0.f}, a1 = a0, a2 = a0, a3 = a0, a4 = a0, a5 = a0;

    { // input projection (h-independent) FIRST: pads the producer-commit window
      const unsigned short* xh = xhi + (((size_t)t*4 + q) << 12);
      const unsigned short* xl = xlo + (((size_t)t*4 + q) << 12);
      #pragma unroll
      for (int kt = 0; kt < 8; ++kt) {
        bfx8 x0 = *(const bfx8*)(xh + (size_t)(kt*64+lane)*8);
        bfx8 x1 = *(const bfx8*)(xl + (size_t)(kt*64+lane)*8);
        if (kt & 1) {
          a3 = MFMA16(x0, wrh[kt], a3); a4 = MFMA16(x0, wrl[kt], a4); a5 = MFMA16(x1, wrh[kt], a5);
        } else {
          a0 = MFMA16(x0, wrh[kt], a0); a1 = MFMA16(x0, wrl[kt], a1); a2 = MFMA16(x1, wrh[kt], a2);
        }
      }
    }

    if (ti > 0) {
      // ---- digest wait: sc0 polls (local L2); every 32nd poll escalates to LLC atomic ----
      int itc = 0;
      for (;;) {
        int v;
        if ((itc++ & 31) == 31) v = __hip_atomic_load(dg + dgi, __ATOMIC_RELAXED, __HIP_MEMORY_SCOPE_AGENT);
        else                    v = (int)ld_sc0_u32(dg + dgi);
        if (__all(v >= ti)) break;
      }
      asm volatile("" ::: "memory");   // keep the bulk loads below the gate
      // ---- bulk h-load: plain coalesced uint4 loads (L1-miss -> local L2 hit) ----
      const int tp = dir ? (t+1) : (t-1);
      const unsigned int* sb = hpk + ((((size_t)dir*S_ + tp)*4 + q) << 13);
      const uint4* sp4 = (const uint4*)sb;
      uint4 qv[8];
      #pragma unroll
      for (int j = 0; j < 8; ++j) qv[j] = sp4[(size_t)(2*j + kts)*128 + tl];
      // ---- sentinel backstop: retry stale words via ATOMIC loads (LLC) ----
      for (;;) {
        bool ok = true;
        #pragma unroll
        for (int j = 0; j < 8; ++j)
          ok &= (qv[j].x != 0xFFFFFFFFu) & (qv[j].y != 0xFFFFFFFFu)
              & (qv[j].z != 0xFFFFFFFFu) & (qv[j].w != 0xFFFFFFFFu);
        if (ok) break;
        const unsigned long long* sq = (const unsigned long long*)sb;
        #pragma unroll
        for (int j = 0; j < 8; ++j) {
          bool bad = (qv[j].x == 0xFFFFFFFFu) | (qv[j].y == 0xFFFFFFFFu)
                   | (qv[j].z == 0xFFFFFFFFu) | (qv[j].w == 0xFFFFFFFFu);
          if (bad) {
            unsigned long long q0 = AL(sq + (size_t)(2*j + kts)*256 + tl*2);
            unsigned long long q1 = AL(sq + (size_t)(2*j + kts)*256 + tl*2 + 1);
            qv[j].x = (unsigned int)q0; qv[j].y = (unsigned int)(q0 >> 32);
            qv[j].z = (unsigned int)q1; qv[j].w = (unsigned int)(q1 >> 32);
          }
        }
      }
      // ---- stage to LDS (hi/lo planes) ----
      unsigned int* shiu = (unsigned int*)sh_hi;
      unsigned int* slou = (unsigned int*)sh_lo;
      #pragma unroll
      for (int j = 0; j < 8; ++j) {
        const int kt = 2*j + kts;
        uint2 hw, lw;
        hw.x = (qv[j].x >> 16)     | (qv[j].y & 0xFFFF0000u);
        lw.x = (qv[j].x & 0xFFFFu) | (qv[j].y << 16);
        hw.y = (qv[j].z >> 16)     | (qv[j].w & 0xFFFF0000u);
        lw.y = (qv[j].z & 0xFFFFu) | (qv[j].w << 16);
        *(uint2*)(shiu + kt*256 + tl*2) = hw;
        *(uint2*)(slou + kt*256 + tl*2) = lw;
      }
    }
    __syncthreads();               // barB: stage visible
    if (ti > 0) {
      #pragma unroll
      for (int kt = 0; kt < 16; ++kt) {
        bfx8 ah = *(const bfx8*)(sh_hi + kt*512 + lane*8);
        bfx8 al = *(const bfx8*)(sh_lo + kt*512 + lane*8);
        bfx8 bh, bl;
        if (kt < 14) {
          bh = *(const bfx8*)(shh + (size_t)((kt*4+wv)*64 + lane)*8);
          bl = *(const bfx8*)(shl + (size_t)((kt*4+wv)*64 + lane)*8);
        } else if (kt == 14) { bh = rbh0; bl = rbl0; }
        else                 { bh = rbh1; bl = rbl1; }
        if (kt & 1) {
          a3 = MFMA16(ah, bh, a3); a4 = MFMA16(ah, bl, a4); a5 = MFMA16(al, bh, a5);
        } else {
          a0 = MFMA16(ah, bh, a0); a1 = MFMA16(ah, bl, a1); a2 = MFMA16(al, bh, a2);
        }
      }
    }

    f32x4 gate = (a0 + a1) + (a2 + a3) + (a4 + a5);
    #pragma unroll
    for (int rr = 0; rr < 4; ++rr)
      gbuf[wv*256 + (((lane>>4)&3)*4+rr)*16 + (lane&15)] = gate[rr];
    __syncthreads();               // barD: gbuf visible
    {
      float gi = gbuf[0*256 + b_l*16 + cc] + bias[0];
      float gf = gbuf[1*256 + b_l*16 + cc] + bias[1];
      float gg = gbuf[2*256 + b_l*16 + cc] + bias[2];
      float go = gbuf[3*256 + b_l*16 + cc] + bias[3];
      float is = sigm(gi), fs = sigm(gf), gs = tanhfast(gg), os = sigm(go);
      cst = fs*cst + is*gs;
      float hv = os * tanhfast(cst);
      unsigned short hh = f2bf(hv);
      unsigned short hl = f2bf(hv - bf2f(hh));
      unsigned int pk = (((unsigned int)hh) << 16) | (unsigned int)hl;
      size_t hidx = ((((size_t)dir*S_ + t)*4 + q) << 13) + (size_t)hkt*512 + hlane*8 + hj;
      // dual-path store: plain (local L2 fast path) + agent-atomic (LLC, any-mapping
      // correctness). Same value to the same address -> interleaving-safe.
      *(volatile unsigned int*)(hpk + hidx) = pk;
      __hip_atomic_store(hpk + hidx, pk, __ATOMIC_RELAXED, __HIP_MEMORY_SCOPE_AGENT);
    }
    // drain all 4 waves' stores (per-wave vmcnt(0) at the barrier: plain acked at L2,
    // atomic acked at LLC) before posting the digest on both paths.
    __syncthreads();
    if (tid == 0) {
      *(volatile int*)(dg + g*32 + r) = ti + 1;
      __hip_atomic_store(dg + g*32 + r, ti + 1, __ATOMIC_RELAXED, __HIP_MEMORY_SCOPE_AGENT);
    }
  }
}

// ---------------- attention scores: one WG per s ----------------
__global__ void __launch_bounds__(256) k_att1(const unsigned int* __restrict__ hpk,
                                              const unsigned short* __restrict__ awhi,
                                              const unsigned short* __restrict__ awlo,
                                              const float* __restrict__ attv,
                                              float* __restrict__ attbuf){
  const int s = blockIdx.x;
  const int tid = threadIdx.x, wv = tid >> 6, lane = tid & 63;
  const int q = wv;
  f32x4 z = {0.f,0.f,0.f,0.f};
  f32x4 acc[4][3];
  #pragma unroll
  for (int nt = 0; nt < 4; ++nt) { acc[nt][0] = z; acc[nt][1] = z; acc[nt][2] = z; }
  for (int kt = 0; kt < 32; ++kt) {
    int dir = kt >> 4, ktt = kt & 15;
    const unsigned int* hb = hpk + ((((size_t)dir*S_ + s)*4 + q) << 13) + ktt*512 + lane*8;
    uint4 u0 = *(const uint4*)hb, u1 = *(const uint4*)(hb + 4);
    bfx8 ah, al; unpack8(u0, u1, ah, al);
    #pragma unroll
    for (int nt = 0; nt < 4; ++nt) {
      bfx8 bh = *(const bfx8*)(awhi + (size_t)((nt*32+kt)*64+lane)*8);
      bfx8 bl = *(const bfx8*)(awlo + (size_t)((nt*32+kt)*64+lane)*8);
      acc[nt][0] = MFMA16(ah, bh, acc[nt][0]);
      acc[nt][1] = MFMA16(ah, bl, acc[nt][1]);
      acc[nt][2] = MFMA16(al, bh, acc[nt][2]);
    }
  }
  float part[4] = {0.f,0.f,0.f,0.f};
  #pragma unroll
  for (int nt = 0; nt < 4; ++nt) {
    f32x4 d = (acc[nt][0] + acc[nt][1]) + acc[nt][2];
    float vvv = attv[nt*16 + (lane&15)];
    #pragma unroll
    for (int rr = 0; rr < 4; ++rr) part[rr] += tanhfast(d[rr]) * vvv;
  }
  #pragma unroll
  for (int m = 1; m < 16; m <<= 1) {
    #pragma unroll
    for (int rr = 0; rr < 4; ++rr) part[rr] += __shfl_xor(part[rr], m, 64);
  }
  if ((lane & 15) == 0) {
    #pragma unroll
    for (int rr = 0; rr < 4; ++rr) {
      int b = q*16 + ((lane>>4)&3)*4 + rr;
      attbuf[(size_t)b*S_ + s] = part[rr];
    }
  }
}

// ---------------- softmax over s per b ----------------
__global__ void __launch_bounds__(256) k_att2(const float* __restrict__ attbuf,
                                              float* __restrict__ wbuf){
  const int b = blockIdx.x, tid = threadIdx.x;
  __shared__ float sm[4];
  float v0 = attbuf[(size_t)b*S_ + tid];
  float v1 = attbuf[(size_t)b*S_ + 256 + tid];
  float m = fmaxf(v0, v1);
  #pragma unroll
  for (int o = 1; o < 64; o <<= 1) m = fmaxf(m, __shfl_xor(m, o, 64));
  if ((tid & 63) == 0) sm[tid >> 6] = m;
  __syncthreads();
  m = fmaxf(fmaxf(sm[0], sm[1]), fmaxf(sm[2], sm[3]));
  __syncthreads();
  float e0 = __expf(v0 - m), e1 = __expf(v1 - m);
  float su = e0 + e1;
  #pragma unroll
  for (int o = 1; o < 64; o <<= 1) su += __shfl_xor(su, o, 64);
  if ((tid & 63) == 0) sm[tid >> 6] = su;
  __syncthreads();
  su = (sm[0] + sm[1]) + (sm[2] + sm[3]);
  wbuf[(size_t)b*S_ + tid]       = e0 / su;
  wbuf[(size_t)b*S_ + 256 + tid] = e1 / su;
}

// ---------------- weighted sum: out[b][2H] ----------------
__global__ void __launch_bounds__(256) k_att3(const unsigned int* __restrict__ hpk,
                                              const float* __restrict__ wbuf,
                                              float* __restrict__ out){
  const int bid = blockIdx.x;              // 128
  const int dir = bid >> 6, q = (bid >> 4) & 3, kt = bid & 15;
  const int tid = threadIdx.x;
  __shared__ float wl[16*512];
  for (int i = tid; i < 16*512; i += 256) {
    int bb = i >> 9, ss = i & 511;
    wl[i] = wbuf[(size_t)(q*16 + bb)*S_ + ss];
  }
  __syncthreads();
  const int l2 = tid >> 2, jj = (tid & 3)*2;
  const int b_l = l2 & 15;
  float acc0 = 0.f, acc1 = 0.f;
  for (int t = 0; t < S_; ++t) {
    const unsigned int* hb = hpk + ((((size_t)dir*S_ + t)*4 + q) << 13) + kt*512 + l2*8 + jj;
    uint2 u = *(const uint2*)hb;
    float w = wl[b_l*512 + t];
    acc0 += w * (bf2f((unsigned short)(u.x >> 16)) + bf2f((unsigned short)(u.x & 0xffffu)));
    acc1 += w * (bf2f((unsigned short)(u.y >> 16)) + bf2f((unsigned short)(u.y & 0xffffu)));
  }
  int k = kt*32 + ((l2 >> 4) & 3)*8 + jj;
  float* o = out + (size_t)(q*16 + b_l)*1024 + dir*512 + k;
  o[0] = acc0;
  o[1] = acc1;
}

// ---------------- launcher ----------------
extern "C" void kernel_launch(void* const* d_in, const int* in_sizes, int n_in,
                              void* d_out, int out_size, void* d_ws, size_t ws_size,
                              hipStream_t stream) {
  const float* x     = (const float*)d_in[0];
  const float* fWih  = (const float*)d_in[1];
  const float* fWhh  = (const float*)d_in[2];
  const float* fbih  = (const float*)d_in[3];
  const float* fbhh  = (const float*)d_in[4];
  const float* bWih  = (const float*)d_in[5];
  const float* bWhh  = (const float*)d_in[6];
  const float* bbih  = (const float*)d_in[7];
  const float* bbhh  = (const float*)d_in[8];
  const float* attW  = (const float*)d_in[9];
  const float* attv  = (const float*)d_in[10];
  float* out = (float*)d_out;

  char* ws = (char*)d_ws;
  const size_t OFF_HPK  = 0;
  const size_t OFF_XHI  = 134217728;            // 128 MB
  const size_t OFF_XLO  = OFF_XHI + 16777216;
  const size_t OFF_WHI  = OFF_XLO + 16777216;   // 160 MB
  const size_t OFF_WLO  = OFF_WHI + 8388608;
  const size_t OFF_AWHI = OFF_WLO + 8388608;    // 176 MB
  const size_t OFF_AWLO = OFF_AWHI + 131072;
  const size_t OFF_ATTB = OFF_AWLO + 131072;
  const size_t OFF_WBUF = OFF_ATTB + 131072;
  const size_t OFF_DG   = OFF_WBUF + 131072;

  unsigned int*   hpk  = (unsigned int*)(ws + OFF_HPK);
  unsigned short* xhi  = (unsigned short*)(ws + OFF_XHI);
  unsigned short* xlo  = (unsigned short*)(ws + OFF_XLO);
  unsigned short* whi  = (unsigned short*)(ws + OFF_WHI);
  unsigned short* wlo  = (unsigned short*)(ws + OFF_WLO);
  unsigned short* awhi = (unsigned short*)(ws + OFF_AWHI);
  unsigned short* awlo = (unsigned short*)(ws + OFF_AWLO);
  float*          attb = (float*)(ws + OFF_ATTB);
  float*          wbuf = (float*)(ws + OFF_WBUF);
  int*            dg   = (int*)(ws + OFF_DG);

  // sentinel-fill the h exchange buffer; zero the epoch digests
  hipMemsetAsync(hpk, 0xFF, 134217728, stream);
  hipMemsetAsync(dg, 0, 4096, stream);

  k_xfrag <<<4096, 256, 0, stream>>>(x, xhi, xlo);
  k_wfrag <<<2048, 256, 0, stream>>>(fWih, bWih, whi, wlo);
  k_awfrag<<<32,   256, 0, stream>>>(attW, awhi, awlo);

  const int LDS_BYTES = 151552;   // 112K Whh + 32K h-stage + 4K gbuf
  hipFuncSetAttribute((const void*)k_lstm, hipFuncAttributeMaxDynamicSharedMemorySize, LDS_BYTES);
  k_lstm<<<256, 256, LDS_BYTES, stream>>>(fWhh, bWhh, fbih, fbhh, bbih, bbhh,
                                          hpk, xhi, xlo, whi, wlo, dg);

  k_att1<<<512, 256, 0, stream>>>(hpk, awhi, awlo, attv, attb);
  k_att2<<<64,  256, 0, stream>>>(attb, wbuf);
  k_att3<<<128, 256, 0, stream>>>(hpk, wbuf, out);
}

// Round 11
// 2634.721 us; speedup vs baseline: 1.1720x; 1.1720x over previous
//
#include <hip/hip_runtime.h>

#define B_ 64
#define S_ 512
#define D_ 256
#define H_ 512

typedef __attribute__((ext_vector_type(8))) short bfx8;
typedef __attribute__((ext_vector_type(4))) float f32x4;

#define MFMA16(a,b,c) __builtin_amdgcn_mfma_f32_16x16x32_bf16((a),(b),(c),0,0,0)
#define AL(p) __hip_atomic_load((p), __ATOMIC_RELAXED, __HIP_MEMORY_SCOPE_AGENT)

__device__ __forceinline__ unsigned short f2bf(float x){
  union { float f; unsigned int u; } v; v.f = x;
  unsigned int r = v.u + 0x7fffu + ((v.u >> 16) & 1u);
  return (unsigned short)(r >> 16);
}
__device__ __forceinline__ float bf2f(unsigned short b){
  union { unsigned int u; float f; } v; v.u = ((unsigned int)b) << 16; return v.f;
}
__device__ __forceinline__ float sigm(float x){ return 1.f/(1.f + __expf(-x)); }
__device__ __forceinline__ float tanhfast(float x){
  float xc = fminf(fmaxf(x, -15.f), 15.f);
  float e = __expf(2.f * xc);
  return (e - 1.f) / (e + 1.f);
}
__device__ __forceinline__ void unpack8(uint4 a, uint4 b, bfx8& hi, bfx8& lo){
  hi[0]=(short)(a.x>>16); lo[0]=(short)(a.x&0xffffu);
  hi[1]=(short)(a.y>>16); lo[1]=(short)(a.y&0xffffu);
  hi[2]=(short)(a.z>>16); lo[2]=(short)(a.z&0xffffu);
  hi[3]=(short)(a.w>>16); lo[3]=(short)(a.w&0xffffu);
  hi[4]=(short)(b.x>>16); lo[4]=(short)(b.x&0xffffu);
  hi[5]=(short)(b.y>>16); lo[5]=(short)(b.y&0xffffu);
  hi[6]=(short)(b.z>>16); lo[6]=(short)(b.z&0xffffu);
  hi[7]=(short)(b.w>>16); lo[7]=(short)(b.w&0xffffu);
}
__device__ __forceinline__ void cvt8(const float* vv, bfx8& hi, bfx8& lo){
  #pragma unroll
  for (int j = 0; j < 8; ++j) {
    unsigned short h = f2bf(vv[j]);
    hi[j] = (short)h;
    lo[j] = (short)f2bf(vv[j] - bf2f(h));
  }
}

// ---------------- prep: x fragments [t][q][kt(8)][lane(64)][8] hi/lo ----------------
__global__ void __launch_bounds__(256) k_xfrag(const float* __restrict__ x,
                                               unsigned short* __restrict__ xhi,
                                               unsigned short* __restrict__ xlo){
  int idx = blockIdx.x*256 + threadIdx.x;            // 2^20 threads
  int lane = idx & 63, kt = (idx>>6)&7, q = (idx>>9)&3, t = idx>>11;
  int b = q*16 + (lane&15);
  int k0 = kt*32 + ((lane>>4)&3)*8;
  const float4* p = (const float4*)(x + ((size_t)b*S_ + t)*D_ + k0);
  float4 v0 = p[0], v1 = p[1];
  float vv[8] = {v0.x,v0.y,v0.z,v0.w,v1.x,v1.y,v1.z,v1.w};
  bfx8 hi, lo; cvt8(vv, hi, lo);
  *(bfx8*)(xhi + (size_t)idx*8) = hi;
  *(bfx8*)(xlo + (size_t)idx*8) = lo;
}

// ---------------- prep: Wih fragments [dir][q][r(32)][kt(8)][nt(4)][lane(64)][8] ----------------
__global__ void __launch_bounds__(256) k_wfrag(const float* __restrict__ fWih,
                                               const float* __restrict__ bWih,
                                               unsigned short* __restrict__ whi,
                                               unsigned short* __restrict__ wlo){
  int idx = blockIdx.x*256 + threadIdx.x;            // 2^19 threads
  int lane = idx & 63, nt = (idx>>6)&3, kt = (idx>>8)&7, r = (idx>>11)&31, dir = (idx>>18)&1;
  int row = nt*512 + r*16 + (lane&15);
  int k0 = kt*32 + ((lane>>4)&3)*8;
  const float* W = dir ? bWih : fWih;
  const float4* p = (const float4*)(W + (size_t)row*D_ + k0);
  float4 v0 = p[0], v1 = p[1];
  float vv[8] = {v0.x,v0.y,v0.z,v0.w,v1.x,v1.y,v1.z,v1.w};
  bfx8 hi, lo; cvt8(vv, hi, lo);
  *(bfx8*)(whi + (size_t)idx*8) = hi;
  *(bfx8*)(wlo + (size_t)idx*8) = lo;
}

// ---------------- prep: att_W fragments [nt(4)][kt(32)][lane(64)][8] ----------------
__global__ void __launch_bounds__(256) k_awfrag(const float* __restrict__ attW,
                                                unsigned short* __restrict__ awhi,
                                                unsigned short* __restrict__ awlo){
  int idx = blockIdx.x*256 + threadIdx.x;            // 8192 threads
  int lane = idx & 63, kt = (idx>>6)&31, nt = idx>>11;
  int n = nt*16 + (lane&15);
  int k0 = kt*32 + ((lane>>4)&3)*8;
  const float4* p = (const float4*)(attW + (size_t)n*1024 + k0);
  float4 v0 = p[0], v1 = p[1];
  float vv[8] = {v0.x,v0.y,v0.z,v0.w,v1.x,v1.y,v1.z,v1.w};
  bfx8 hi, lo; cvt8(vv, hi, lo);
  *(bfx8*)(awhi + (size_t)idx*8) = hi;
  *(bfx8*)(awlo + (size_t)idx*8) = lo;
}

// ---------------- main recurrence: 256 WGs = 8 groups(dir x quarter) x 32 col-WGs ----------------
// ROTATING HOT EXCHANGE: h for step ti goes to hx[dir][q][ti&1] (512 KB total, lines
// rewritten every step -> LLC-resident, ~300cy legs instead of ~1000cy HBM legs), via
// agent-atomic stores. Full history goes to hpk with PLAIN streaming stores (read only by
// the attention kernels after this kernel ends). Ordering: producer __syncthreads (vmcnt0
// drain of both stores) before posting the digest; consumers read the exchange with
// agent-atomic u64 loads (L2-bypass -- required since a consumer's own XCD L2 may hold the
// slot line from step ti-2 and there is no cross-XCD invalidation).
// Depth-2 overwrite safety: a WG reaches iteration ti+2 (overwriting slot ti&1) only after
// the digest shows all peers completed ti+1, i.e. all peers already READ slot ti&1.
__global__ void __launch_bounds__(256,1) k_lstm(
    const float* __restrict__ fWhh, const float* __restrict__ bWhh,
    const float* __restrict__ fbih, const float* __restrict__ fbhh,
    const float* __restrict__ bbih, const float* __restrict__ bbhh,
    unsigned int* __restrict__ hpk,          // 128 MB history (plain stores, attention input)
    unsigned int* __restrict__ hx,           // 512 KB rotating exchange (atomic)
    const unsigned short* __restrict__ xhi, const unsigned short* __restrict__ xlo,
    const unsigned short* __restrict__ whi, const unsigned short* __restrict__ wlo,
    int* __restrict__ dg)
{
  extern __shared__ char smem[];
  unsigned short* shh   = (unsigned short*)smem;            // Whh hi frags kt0..13 = 57344 B
  unsigned short* shl   = shh + 28672;                      // Whh lo frags kt0..13 = 57344 B
  unsigned short* sh_hi = (unsigned short*)(smem + 114688); // staged h hi [kt16][lane64][8] = 16 KB
  unsigned short* sh_lo = sh_hi + 8192;                     // staged h lo = 16 KB
  float* gbuf = (float*)(smem + 147456);                    // dedicated gate exchange [4][16][16] = 4 KB

  const int tid = threadIdx.x, bid = blockIdx.x;
  const int g = bid & 7, r = bid >> 3;
  const int dir = g >> 2, q = g & 3;
  const int wv = tid >> 6, lane = tid & 63;
  const float* Whh = dir ? bWhh : fWhh;

  // stage Whh slice: kt 0..13 -> LDS fragments; kt 14,15 -> registers (exact per-thread match)
  bfx8 rbh0, rbl0, rbh1, rbl1;
  #pragma unroll
  for (int i = 0; i < 16; ++i) {
    int fl = tid & 63, fnt = (tid>>6)&3;
    int row = fnt*512 + r*16 + (fl&15);
    int k0 = i*32 + ((fl>>4)&3)*8;
    const float4* p = (const float4*)(Whh + (size_t)row*H_ + k0);
    float4 v0 = p[0], v1 = p[1];
    float vv[8] = {v0.x,v0.y,v0.z,v0.w,v1.x,v1.y,v1.z,v1.w};
    bfx8 hi, lo; cvt8(vv, hi, lo);
    if (i < 14) {
      *(bfx8*)(shh + (size_t)((i*4+fnt)*64+fl)*8) = hi;
      *(bfx8*)(shl + (size_t)((i*4+fnt)*64+fl)*8) = lo;
    } else if (i == 14) { rbh0 = hi; rbl0 = lo; }
    else                { rbh1 = hi; rbl1 = lo; }
  }

  // Wih fragments -> registers (constant across steps)
  bfx8 wrh[8], wrl[8];
  {
    const size_t wb = (((size_t)(dir*4+q)*32 + r)*32 + wv)*64;
    #pragma unroll
    for (int kt = 0; kt < 8; ++kt) {
      wrh[kt] = *(const bfx8*)(whi + (wb + kt*256 + lane)*8);
      wrl[kt] = *(const bfx8*)(wlo + (wb + kt*256 + lane)*8);
    }
  }

  const int b_l = tid >> 4, cc = tid & 15;
  const int jcol = r*16 + cc;
  const float* bih = dir ? bbih : fbih;
  const float* bhh = dir ? bbhh : fbhh;
  float bias[4];
  #pragma unroll
  for (int gt = 0; gt < 4; ++gt) bias[gt] = bih[gt*512 + jcol] + bhh[gt*512 + jcol];
  float cst = 0.f;
  const int hkt   = jcol >> 5;
  const int hlane = ((jcol>>3)&3)*16 + b_l;
  const int hj    = jcol & 7;
  const int dgi   = g*32 + (lane & 31);     // each lane polls one producer's epoch word
  __syncthreads();

  for (int ti = 0; ti < S_; ++ti) {
    const int t = dir ? (S_-1-ti) : ti;
    f32x4 a0 = {0.f,0.f,0.f,0.f}, a1 = a0, a2 = a0, a3 = a0, a4 = a0, a5 = a0;

    { // input projection (h-independent) FIRST: pads the producer-commit window
      const unsigned short* xh = xhi + (((size_t)t*4 + q) << 12);
      const unsigned short* xl = xlo + (((size_t)t*4 + q) << 12);
      #pragma unroll
      for (int kt = 0; kt < 8; ++kt) {
        bfx8 x0 = *(const bfx8*)(xh + (size_t)(kt*64+lane)*8);
        bfx8 x1 = *(const bfx8*)(xl + (size_t)(kt*64+lane)*8);
        if (kt & 1) {
          a3 = MFMA16(x0, wrh[kt], a3); a4 = MFMA16(x0, wrl[kt], a4); a5 = MFMA16(x1, wrh[kt], a5);
        } else {
          a0 = MFMA16(x0, wrh[kt], a0); a1 = MFMA16(x0, wrl[kt], a1); a2 = MFMA16(x1, wrh[kt], a2);
        }
      }
    }

    if (ti > 0) {
      // ---- digest wait: one 128B line per group ----
      for (;;) {
        int v = __hip_atomic_load(dg + dgi, __ATOMIC_RELAXED, __HIP_MEMORY_SCOPE_AGENT);
        if (__all(v >= ti)) break;
      }
      asm volatile("" ::: "memory");   // keep the bulk loads below the gate
      // ---- bulk h-load from the HOT rotating slot (agent-atomic u64, LLC-served) ----
      const unsigned long long* sp =
          (const unsigned long long*)(hx + ((((size_t)(dir*4 + q))*2 + ((ti-1)&1)) << 13));
      unsigned long long qs[16];
      #pragma unroll
      for (int i = 0; i < 16; ++i) qs[i] = AL(sp + i*256 + tid);
      // ---- stage to LDS (hi/lo planes, conflict-free b32 writes) ----
      #pragma unroll
      for (int i = 0; i < 16; ++i) {
        unsigned int e0 = (unsigned int)qs[i], e1 = (unsigned int)(qs[i] >> 32);
        *(unsigned int*)(sh_hi + i*512 + tid*2) = (e0 >> 16)     | (e1 & 0xFFFF0000u);
        *(unsigned int*)(sh_lo + i*512 + tid*2) = (e0 & 0xFFFFu) | (e1 << 16);
      }
    }
    __syncthreads();               // barB: stage visible
    if (ti > 0) {
      #pragma unroll
      for (int kt = 0; kt < 16; ++kt) {
        bfx8 ah = *(const bfx8*)(sh_hi + kt*512 + lane*8);
        bfx8 al = *(const bfx8*)(sh_lo + kt*512 + lane*8);
        bfx8 bh, bl;
        if (kt < 14) {
          bh = *(const bfx8*)(shh + (size_t)((kt*4+wv)*64 + lane)*8);
          bl = *(const bfx8*)(shl + (size_t)((kt*4+wv)*64 + lane)*8);
        } else if (kt == 14) { bh = rbh0; bl = rbl0; }
        else                 { bh = rbh1; bl = rbl1; }
        if (kt & 1) {
          a3 = MFMA16(ah, bh, a3); a4 = MFMA16(ah, bl, a4); a5 = MFMA16(al, bh, a5);
        } else {
          a0 = MFMA16(ah, bh, a0); a1 = MFMA16(ah, bl, a1); a2 = MFMA16(al, bh, a2);
        }
      }
    }

    f32x4 gate = (a0 + a1) + (a2 + a3) + (a4 + a5);
    #pragma unroll
    for (int rr = 0; rr < 4; ++rr)
      gbuf[wv*256 + (((lane>>4)&3)*4+rr)*16 + (lane&15)] = gate[rr];
    __syncthreads();               // barD: gbuf visible
    {
      float gi = gbuf[0*256 + b_l*16 + cc] + bias[0];
      float gf = gbuf[1*256 + b_l*16 + cc] + bias[1];
      float gg = gbuf[2*256 + b_l*16 + cc] + bias[2];
      float go = gbuf[3*256 + b_l*16 + cc] + bias[3];
      float is = sigm(gi), fs = sigm(gf), gs = tanhfast(gg), os = sigm(go);
      cst = fs*cst + is*gs;
      float hv = os * tanhfast(cst);
      unsigned short hh = f2bf(hv);
      unsigned short hl = f2bf(hv - bf2f(hh));
      unsigned int pk = (((unsigned int)hh) << 16) | (unsigned int)hl;
      size_t hoff = (size_t)hkt*512 + hlane*8 + hj;
      // history: plain streaming store (attention reads it after this kernel)
      hpk[((((size_t)dir*S_ + t)*4 + q) << 13) + hoff] = pk;
      // exchange: agent-atomic store to the hot rotating slot
      __hip_atomic_store(hx + ((((size_t)(dir*4 + q))*2 + (ti&1)) << 13) + hoff, pk,
                         __ATOMIC_RELAXED, __HIP_MEMORY_SCOPE_AGENT);
    }
    // drain all 4 waves' stores (per-wave vmcnt(0) at the barrier) before posting
    __syncthreads();
    if (tid == 0)
      __hip_atomic_store(dg + g*32 + r, ti + 1, __ATOMIC_RELAXED, __HIP_MEMORY_SCOPE_AGENT);
  }
}

// ---------------- attention scores: one WG per s ----------------
__global__ void __launch_bounds__(256) k_att1(const unsigned int* __restrict__ hpk,
                                              const unsigned short* __restrict__ awhi,
                                              const unsigned short* __restrict__ awlo,
                                              const float* __restrict__ attv,
                                              float* __restrict__ attbuf){
  const int s = blockIdx.x;
  const int tid = threadIdx.x, wv = tid >> 6, lane = tid & 63;
  const int q = wv;
  f32x4 z = {0.f,0.f,0.f,0.f};
  f32x4 acc[4][3];
  #pragma unroll
  for (int nt = 0; nt < 4; ++nt) { acc[nt][0] = z; acc[nt][1] = z; acc[nt][2] = z; }
  for (int kt = 0; kt < 32; ++kt) {
    int dir = kt >> 4, ktt = kt & 15;
    const unsigned int* hb = hpk + ((((size_t)dir*S_ + s)*4 + q) << 13) + ktt*512 + lane*8;
    uint4 u0 = *(const uint4*)hb, u1 = *(const uint4*)(hb + 4);
    bfx8 ah, al; unpack8(u0, u1, ah, al);
    #pragma unroll
    for (int nt = 0; nt < 4; ++nt) {
      bfx8 bh = *(const bfx8*)(awhi + (size_t)((nt*32+kt)*64+lane)*8);
      bfx8 bl = *(const bfx8*)(awlo + (size_t)((nt*32+kt)*64+lane)*8);
      acc[nt][0] = MFMA16(ah, bh, acc[nt][0]);
      acc[nt][1] = MFMA16(ah, bl, acc[nt][1]);
      acc[nt][2] = MFMA16(al, bh, acc[nt][2]);
    }
  }
  float part[4] = {0.f,0.f,0.f,0.f};
  #pragma unroll
  for (int nt = 0; nt < 4; ++nt) {
    f32x4 d = (acc[nt][0] + acc[nt][1]) + acc[nt][2];
    float vvv = attv[nt*16 + (lane&15)];
    #pragma unroll
    for (int rr = 0; rr < 4; ++rr) part[rr] += tanhfast(d[rr]) * vvv;
  }
  #pragma unroll
  for (int m = 1; m < 16; m <<= 1) {
    #pragma unroll
    for (int rr = 0; rr < 4; ++rr) part[rr] += __shfl_xor(part[rr], m, 64);
  }
  if ((lane & 15) == 0) {
    #pragma unroll
    for (int rr = 0; rr < 4; ++rr) {
      int b = q*16 + ((lane>>4)&3)*4 + rr;
      attbuf[(size_t)b*S_ + s] = part[rr];
    }
  }
}

// ---------------- softmax over s per b ----------------
__global__ void __launch_bounds__(256) k_att2(const float* __restrict__ attbuf,
                                              float* __restrict__ wbuf){
  const int b = blockIdx.x, tid = threadIdx.x;
  __shared__ float sm[4];
  float v0 = attbuf[(size_t)b*S_ + tid];
  float v1 = attbuf[(size_t)b*S_ + 256 + tid];
  float m = fmaxf(v0, v1);
  #pragma unroll
  for (int o = 1; o < 64; o <<= 1) m = fmaxf(m, __shfl_xor(m, o, 64));
  if ((tid & 63) == 0) sm[tid >> 6] = m;
  __syncthreads();
  m = fmaxf(fmaxf(sm[0], sm[1]), fmaxf(sm[2], sm[3]));
  __syncthreads();
  float e0 = __expf(v0 - m), e1 = __expf(v1 - m);
  float su = e0 + e1;
  #pragma unroll
  for (int o = 1; o < 64; o <<= 1) su += __shfl_xor(su, o, 64);
  if ((tid & 63) == 0) sm[tid >> 6] = su;
  __syncthreads();
  su = (sm[0] + sm[1]) + (sm[2] + sm[3]);
  wbuf[(size_t)b*S_ + tid]       = e0 / su;
  wbuf[(size_t)b*S_ + 256 + tid] = e1 / su;
}

// ---------------- weighted sum: out[b][2H] ----------------
__global__ void __launch_bounds__(256) k_att3(const unsigned int* __restrict__ hpk,
                                              const float* __restrict__ wbuf,
                                              float* __restrict__ out){
  const int bid = blockIdx.x;              // 128
  const int dir = bid >> 6, q = (bid >> 4) & 3, kt = bid & 15;
  const int tid = threadIdx.x;
  __shared__ float wl[16*512];
  for (int i = tid; i < 16*512; i += 256) {
    int bb = i >> 9, ss = i & 511;
    wl[i] = wbuf[(size_t)(q*16 + bb)*S_ + ss];
  }
  __syncthreads();
  const int l2 = tid >> 2, jj = (tid & 3)*2;
  const int b_l = l2 & 15;
  float acc0 = 0.f, acc1 = 0.f;
  for (int t = 0; t < S_; ++t) {
    const unsigned int* hb = hpk + ((((size_t)dir*S_ + t)*4 + q) << 13) + kt*512 + l2*8 + jj;
    uint2 u = *(const uint2*)hb;
    float w = wl[b_l*512 + t];
    acc0 += w * (bf2f((unsigned short)(u.x >> 16)) + bf2f((unsigned short)(u.x & 0xffffu)));
    acc1 += w * (bf2f((unsigned short)(u.y >> 16)) + bf2f((unsigned short)(u.y & 0xffffu)));
  }
  int k = kt*32 + ((l2 >> 4) & 3)*8 + jj;
  float* o = out + (size_t)(q*16 + b_l)*1024 + dir*512 + k;
  o[0] = acc0;
  o[1] = acc1;
}

// ---------------- launcher ----------------
extern "C" void kernel_launch(void* const* d_in, const int* in_sizes, int n_in,
                              void* d_out, int out_size, void* d_ws, size_t ws_size,
                              hipStream_t stream) {
  const float* x     = (const float*)d_in[0];
  const float* fWih  = (const float*)d_in[1];
  const float* fWhh  = (const float*)d_in[2];
  const float* fbih  = (const float*)d_in[3];
  const float* fbhh  = (const float*)d_in[4];
  const float* bWih  = (const float*)d_in[5];
  const float* bWhh  = (const float*)d_in[6];
  const float* bbih  = (const float*)d_in[7];
  const float* bbhh  = (const float*)d_in[8];
  const float* attW  = (const float*)d_in[9];
  const float* attv  = (const float*)d_in[10];
  float* out = (float*)d_out;

  char* ws = (char*)d_ws;
  const size_t OFF_HPK  = 0;
  const size_t OFF_XHI  = 134217728;            // 128 MB
  const size_t OFF_XLO  = OFF_XHI + 16777216;
  const size_t OFF_WHI  = OFF_XLO + 16777216;   // 160 MB
  const size_t OFF_WLO  = OFF_WHI + 8388608;
  const size_t OFF_AWHI = OFF_WLO + 8388608;    // 176 MB
  const size_t OFF_AWLO = OFF_AWHI + 131072;
  const size_t OFF_ATTB = OFF_AWLO + 131072;
  const size_t OFF_WBUF = OFF_ATTB + 131072;
  const size_t OFF_DG   = OFF_WBUF + 131072;
  const size_t OFF_HX   = OFF_DG + 4096;        // 512 KB rotating exchange

  unsigned int*   hpk  = (unsigned int*)(ws + OFF_HPK);
  unsigned short* xhi  = (unsigned short*)(ws + OFF_XHI);
  unsigned short* xlo  = (unsigned short*)(ws + OFF_XLO);
  unsigned short* whi  = (unsigned short*)(ws + OFF_WHI);
  unsigned short* wlo  = (unsigned short*)(ws + OFF_WLO);
  unsigned short* awhi = (unsigned short*)(ws + OFF_AWHI);
  unsigned short* awlo = (unsigned short*)(ws + OFF_AWLO);
  float*          attb = (float*)(ws + OFF_ATTB);
  float*          wbuf = (float*)(ws + OFF_WBUF);
  int*            dg   = (int*)(ws + OFF_DG);
  unsigned int*   hx   = (unsigned int*)(ws + OFF_HX);

  // zero the epoch digests (no 128 MB sentinel fill anymore — digest gates all reads)
  hipMemsetAsync(dg, 0, 4096, stream);

  k_xfrag <<<4096, 256, 0, stream>>>(x, xhi, xlo);
  k_wfrag <<<2048, 256, 0, stream>>>(fWih, bWih, whi, wlo);
  k_awfrag<<<32,   256, 0, stream>>>(attW, awhi, awlo);

  const int LDS_BYTES = 151552;   // 112K Whh + 32K h-stage + 4K gbuf
  hipFuncSetAttribute((const void*)k_lstm, hipFuncAttributeMaxDynamicSharedMemorySize, LDS_BYTES);
  k_lstm<<<256, 256, LDS_BYTES, stream>>>(fWhh, bWhh, fbih, fbhh, bbih, bbhh,
                                          hpk, hx, xhi, xlo, whi, wlo, dg);

  k_att1<<<512, 256, 0, stream>>>(hpk, awhi, awlo, attv, attb);
  k_att2<<<64,  256, 0, stream>>>(attb, wbuf);
  k_att3<<<128, 256, 0, stream>>>(hpk, wbuf, out);
}

// Round 12
// 1929.765 us; speedup vs baseline: 1.6002x; 1.3653x over previous
//
#include <hip/hip_runtime.h>

#define B_ 64
#define S_ 512
#define D_ 256
#define H_ 512

typedef __attribute__((ext_vector_type(8))) short bfx8;
typedef __attribute__((ext_vector_type(4))) float f32x4;

#define MFMA16(a,b,c) __builtin_amdgcn_mfma_f32_16x16x32_bf16((a),(b),(c),0,0,0)
#define AL(p)  __hip_atomic_load((p), __ATOMIC_RELAXED, __HIP_MEMORY_SCOPE_AGENT)
#define ALI(p) __hip_atomic_load((p), __ATOMIC_RELAXED, __HIP_MEMORY_SCOPE_AGENT)

__device__ __forceinline__ unsigned short f2bf(float x){
  union { float f; unsigned int u; } v; v.f = x;
  unsigned int r = v.u + 0x7fffu + ((v.u >> 16) & 1u);
  return (unsigned short)(r >> 16);
}
__device__ __forceinline__ float bf2f(unsigned short b){
  union { unsigned int u; float f; } v; v.u = ((unsigned int)b) << 16; return v.f;
}
__device__ __forceinline__ float sigm(float x){ return 1.f/(1.f + __expf(-x)); }
__device__ __forceinline__ float tanhfast(float x){
  float xc = fminf(fmaxf(x, -15.f), 15.f);
  float e = __expf(2.f * xc);
  return (e - 1.f) / (e + 1.f);
}
__device__ __forceinline__ void unpack8(uint4 a, uint4 b, bfx8& hi, bfx8& lo){
  hi[0]=(short)(a.x>>16); lo[0]=(short)(a.x&0xffffu);
  hi[1]=(short)(a.y>>16); lo[1]=(short)(a.y&0xffffu);
  hi[2]=(short)(a.z>>16); lo[2]=(short)(a.z&0xffffu);
  hi[3]=(short)(a.w>>16); lo[3]=(short)(a.w&0xffffu);
  hi[4]=(short)(b.x>>16); lo[4]=(short)(b.x&0xffffu);
  hi[5]=(short)(b.y>>16); lo[5]=(short)(b.y&0xffffu);
  hi[6]=(short)(b.z>>16); lo[6]=(short)(b.z&0xffffu);
  hi[7]=(short)(b.w>>16); lo[7]=(short)(b.w&0xffffu);
}
__device__ __forceinline__ void cvt8(const float* vv, bfx8& hi, bfx8& lo){
  #pragma unroll
  for (int j = 0; j < 8; ++j) {
    unsigned short h = f2bf(vv[j]);
    hi[j] = (short)h;
    lo[j] = (short)f2bf(vv[j] - bf2f(h));
  }
}

// ---------------- prep: x fragments [t][q][kt(8)][lane(64)][8] hi/lo ----------------
__global__ void __launch_bounds__(256) k_xfrag(const float* __restrict__ x,
                                               unsigned short* __restrict__ xhi,
                                               unsigned short* __restrict__ xlo){
  int idx = blockIdx.x*256 + threadIdx.x;            // 2^20 threads
  int lane = idx & 63, kt = (idx>>6)&7, q = (idx>>9)&3, t = idx>>11;
  int b = q*16 + (lane&15);
  int k0 = kt*32 + ((lane>>4)&3)*8;
  const float4* p = (const float4*)(x + ((size_t)b*S_ + t)*D_ + k0);
  float4 v0 = p[0], v1 = p[1];
  float vv[8] = {v0.x,v0.y,v0.z,v0.w,v1.x,v1.y,v1.z,v1.w};
  bfx8 hi, lo; cvt8(vv, hi, lo);
  *(bfx8*)(xhi + (size_t)idx*8) = hi;
  *(bfx8*)(xlo + (size_t)idx*8) = lo;
}

// ---------------- prep: Wih fragments [dir][q][r(32)][kt(8)][nt(4)][lane(64)][8] ----------------
__global__ void __launch_bounds__(256) k_wfrag(const float* __restrict__ fWih,
                                               const float* __restrict__ bWih,
                                               unsigned short* __restrict__ whi,
                                               unsigned short* __restrict__ wlo){
  int idx = blockIdx.x*256 + threadIdx.x;            // 2^19 threads
  int lane = idx & 63, nt = (idx>>6)&3, kt = (idx>>8)&7, r = (idx>>11)&31, dir = (idx>>18)&1;
  int row = nt*512 + r*16 + (lane&15);
  int k0 = kt*32 + ((lane>>4)&3)*8;
  const float* W = dir ? bWih : fWih;
  const float4* p = (const float4*)(W + (size_t)row*D_ + k0);
  float4 v0 = p[0], v1 = p[1];
  float vv[8] = {v0.x,v0.y,v0.z,v0.w,v1.x,v1.y,v1.z,v1.w};
  bfx8 hi, lo; cvt8(vv, hi, lo);
  *(bfx8*)(whi + (size_t)idx*8) = hi;
  *(bfx8*)(wlo + (size_t)idx*8) = lo;
}

// ---------------- prep: att_W fragments [nt(4)][kt(32)][lane(64)][8] ----------------
__global__ void __launch_bounds__(256) k_awfrag(const float* __restrict__ attW,
                                                unsigned short* __restrict__ awhi,
                                                unsigned short* __restrict__ awlo){
  int idx = blockIdx.x*256 + threadIdx.x;            // 8192 threads
  int lane = idx & 63, kt = (idx>>6)&31, nt = idx>>11;
  int n = nt*16 + (lane&15);
  int k0 = kt*32 + ((lane>>4)&3)*8;
  const float4* p = (const float4*)(attW + (size_t)n*1024 + k0);
  float4 v0 = p[0], v1 = p[1];
  float vv[8] = {v0.x,v0.y,v0.z,v0.w,v1.x,v1.y,v1.z,v1.w};
  bfx8 hi, lo; cvt8(vv, hi, lo);
  *(bfx8*)(awhi + (size_t)idx*8) = hi;
  *(bfx8*)(awlo + (size_t)idx*8) = lo;
}

// ---------------- main recurrence: 256 WGs = 8 groups(dir x quarter) x 32 col-WGs ----------------
// R11 rotating hot exchange +
//  (1) x-fragment SOFTWARE PIPELINE: step t+1's 16KB x-block is loaded into registers at
//      step t top (HBM latency hides under the rendezvous) and written to a 2x16KB LDS
//      ping-pong after the digest wait; step t's x-MFMAs read LDS only.
//  (2) PER-WAVE digest post: each wave s_waitcnt vmcnt(0)'s its own h-stores then lane0
//      posts its epoch word -- no final __syncthreads/cross-wave drain in the chain.
//      Consumer waits for all 128 wave-words; passing the wait implies every wave finished
//      its epilogue (read gbuf) and h-MFMA (read stage) => 2 barriers/step remain safe.
__global__ void __launch_bounds__(256,1) k_lstm(
    const float* __restrict__ fWhh, const float* __restrict__ bWhh,
    const float* __restrict__ fbih, const float* __restrict__ fbhh,
    const float* __restrict__ bbih, const float* __restrict__ bbhh,
    unsigned int* __restrict__ hpk,          // 128 MB history (plain stores, attention input)
    unsigned int* __restrict__ hx,           // 512 KB rotating exchange (atomic)
    const unsigned short* __restrict__ xhi, const unsigned short* __restrict__ xlo,
    const unsigned short* __restrict__ whi, const unsigned short* __restrict__ wlo,
    int* __restrict__ dg)
{
  extern __shared__ char smem[];
  unsigned short* shh   = (unsigned short*)smem;            // Whh hi frags kt0..9 = 40960 B
  unsigned short* shl   = shh + 20480;                      // Whh lo frags kt0..9 = 40960 B
  unsigned short* sh_hi = (unsigned short*)(smem + 81920);  // staged h hi [kt16][lane64][8] = 16 KB
  unsigned short* sh_lo = sh_hi + 8192;                     // staged h lo = 16 KB
  float* gbuf = (float*)(smem + 114688);                    // gate exchange [4][16][16] = 4 KB
  char*  xbuf = smem + 118784;                              // x frags ping-pong 2 x 16 KB

  const int tid = threadIdx.x, bid = blockIdx.x;
  const int g = bid & 7, r = bid >> 3;
  const int dir = g >> 2, q = g & 3;
  const int wv = tid >> 6, lane = tid & 63;
  const float* Whh = dir ? bWhh : fWhh;

  // stage Whh slice: kt 0..9 -> LDS fragments; kt 10..15 -> registers
  bfx8 rbh[6], rbl[6];
  #pragma unroll
  for (int i = 0; i < 16; ++i) {
    int fl = tid & 63, fnt = (tid>>6)&3;
    int row = fnt*512 + r*16 + (fl&15);
    int k0 = i*32 + ((fl>>4)&3)*8;
    const float4* p = (const float4*)(Whh + (size_t)row*H_ + k0);
    float4 v0 = p[0], v1 = p[1];
    float vv[8] = {v0.x,v0.y,v0.z,v0.w,v1.x,v1.y,v1.z,v1.w};
    bfx8 hi, lo; cvt8(vv, hi, lo);
    if (i < 10) {
      *(bfx8*)(shh + (size_t)((i*4+fnt)*64+fl)*8) = hi;
      *(bfx8*)(shl + (size_t)((i*4+fnt)*64+fl)*8) = lo;
    } else { rbh[i-10] = hi; rbl[i-10] = lo; }
  }

  // Wih fragments -> registers (constant across steps)
  bfx8 wrh[8], wrl[8];
  {
    const size_t wb = (((size_t)(dir*4+q)*32 + r)*32 + wv)*64;
    #pragma unroll
    for (int kt = 0; kt < 8; ++kt) {
      wrh[kt] = *(const bfx8*)(whi + (wb + kt*256 + lane)*8);
      wrl[kt] = *(const bfx8*)(wlo + (wb + kt*256 + lane)*8);
    }
  }

  const int b_l = tid >> 4, cc = tid & 15;
  const int jcol = r*16 + cc;
  const float* bih = dir ? bbih : fbih;
  const float* bhh = dir ? bbhh : fbhh;
  float bias[4];
  #pragma unroll
  for (int gt = 0; gt < 4; ++gt) bias[gt] = bih[gt*512 + jcol] + bhh[gt*512 + jcol];
  float cst = 0.f;
  const int hkt   = jcol >> 5;
  const int hlane = ((jcol>>3)&3)*16 + b_l;
  const int hj    = jcol & 7;
  const int d0    = g*128 + lane*2;        // each lane polls 2 of the 128 wave-epoch words

  { // prologue: preload step-0 x block into xbuf[0]
    const int t0 = dir ? (S_-1) : 0;
    const char* hsrc = (const char*)(xhi + (((size_t)t0*4+q) << 12));
    const char* lsrc = (const char*)(xlo + (((size_t)t0*4+q) << 12));
    *(uint4*)(xbuf + tid*16)          = *(const uint4*)(hsrc + tid*16);
    *(uint4*)(xbuf + 4096 + tid*16)   = *(const uint4*)(hsrc + 4096 + tid*16);
    *(uint4*)(xbuf + 8192 + tid*16)   = *(const uint4*)(lsrc + tid*16);
    *(uint4*)(xbuf + 12288 + tid*16)  = *(const uint4*)(lsrc + 4096 + tid*16);
  }
  __syncthreads();

  for (int ti = 0; ti < S_; ++ti) {
    const int t = dir ? (S_-1-ti) : ti;
    char* xb  = xbuf + ((ti)&1)*16384;
    char* xbn = xbuf + ((ti+1)&1)*16384;
    f32x4 a0 = {0.f,0.f,0.f,0.f}, a1 = a0, a2 = a0, a3 = a0, a4 = a0, a5 = a0;

    // ---- issue next step's x-block loads (16B/lane x4, coalesced; land under rendezvous) ----
    uint4 xr0, xr1, xr2, xr3;
    const bool pf = (ti + 1 < S_);
    if (pf) {
      const int tn = dir ? (S_-1-(ti+1)) : (ti+1);
      const char* hsrc = (const char*)(xhi + (((size_t)tn*4+q) << 12));
      const char* lsrc = (const char*)(xlo + (((size_t)tn*4+q) << 12));
      xr0 = *(const uint4*)(hsrc + tid*16);
      xr1 = *(const uint4*)(hsrc + 4096 + tid*16);
      xr2 = *(const uint4*)(lsrc + tid*16);
      xr3 = *(const uint4*)(lsrc + 4096 + tid*16);
    }

    { // input projection from LDS (h-independent)
      const unsigned short* xh = (const unsigned short*)xb;
      const unsigned short* xl = (const unsigned short*)(xb + 8192);
      #pragma unroll
      for (int kt = 0; kt < 8; ++kt) {
        bfx8 x0 = *(const bfx8*)(xh + (size_t)(kt*64+lane)*8);
        bfx8 x1 = *(const bfx8*)(xl + (size_t)(kt*64+lane)*8);
        if (kt & 1) {
          a3 = MFMA16(x0, wrh[kt], a3); a4 = MFMA16(x0, wrl[kt], a4); a5 = MFMA16(x1, wrh[kt], a5);
        } else {
          a0 = MFMA16(x0, wrh[kt], a0); a1 = MFMA16(x0, wrl[kt], a1); a2 = MFMA16(x1, wrh[kt], a2);
        }
      }
    }

    if (ti > 0) {
      // ---- digest wait: 128 wave-epoch words per group, 2 per lane ----
      for (;;) {
        int v0 = ALI(dg + d0), v1 = ALI(dg + d0 + 1);
        if (__all((v0 >= ti) & (v1 >= ti))) break;
      }
      asm volatile("" ::: "memory");
      // ---- bulk h-load from the hot rotating slot ----
      const unsigned long long* sp =
          (const unsigned long long*)(hx + ((((size_t)(dir*4 + q))*2 + ((ti-1)&1)) << 13));
      unsigned long long qs[16];
      #pragma unroll
      for (int i = 0; i < 16; ++i) qs[i] = AL(sp + i*256 + tid);
      // ---- stage to LDS (hi/lo planes) ----
      #pragma unroll
      for (int i = 0; i < 16; ++i) {
        unsigned int e0 = (unsigned int)qs[i], e1 = (unsigned int)(qs[i] >> 32);
        *(unsigned int*)(sh_hi + i*512 + tid*2) = (e0 >> 16)     | (e1 & 0xFFFF0000u);
        *(unsigned int*)(sh_lo + i*512 + tid*2) = (e0 & 0xFFFFu) | (e1 << 16);
      }
    }
    // ---- write the prefetched x-block into the other ping-pong half ----
    if (pf) {
      *(uint4*)(xbn + tid*16)         = xr0;
      *(uint4*)(xbn + 4096 + tid*16)  = xr1;
      *(uint4*)(xbn + 8192 + tid*16)  = xr2;
      *(uint4*)(xbn + 12288 + tid*16) = xr3;
    }
    __syncthreads();               // barB: stage + xbuf visible
    if (ti > 0) {
      #pragma unroll
      for (int kt = 0; kt < 16; ++kt) {
        bfx8 ah = *(const bfx8*)(sh_hi + kt*512 + lane*8);
        bfx8 al = *(const bfx8*)(sh_lo + kt*512 + lane*8);
        bfx8 bh, bl;
        if (kt < 10) {
          bh = *(const bfx8*)(shh + (size_t)((kt*4+wv)*64 + lane)*8);
          bl = *(const bfx8*)(shl + (size_t)((kt*4+wv)*64 + lane)*8);
        } else { bh = rbh[kt-10]; bl = rbl[kt-10]; }
        if (kt & 1) {
          a3 = MFMA16(ah, bh, a3); a4 = MFMA16(ah, bl, a4); a5 = MFMA16(al, bh, a5);
        } else {
          a0 = MFMA16(ah, bh, a0); a1 = MFMA16(ah, bl, a1); a2 = MFMA16(al, bh, a2);
        }
      }
    }

    f32x4 gate = (a0 + a1) + (a2 + a3) + (a4 + a5);
    #pragma unroll
    for (int rr = 0; rr < 4; ++rr)
      gbuf[wv*256 + (((lane>>4)&3)*4+rr)*16 + (lane&15)] = gate[rr];
    __syncthreads();               // barD: gbuf visible
    {
      float gi = gbuf[0*256 + b_l*16 + cc] + bias[0];
      float gf = gbuf[1*256 + b_l*16 + cc] + bias[1];
      float gg = gbuf[2*256 + b_l*16 + cc] + bias[2];
      float go = gbuf[3*256 + b_l*16 + cc] + bias[3];
      float is = sigm(gi), fs = sigm(gf), gs = tanhfast(gg), os = sigm(go);
      cst = fs*cst + is*gs;
      float hv = os * tanhfast(cst);
      unsigned short hh = f2bf(hv);
      unsigned short hl = f2bf(hv - bf2f(hh));
      unsigned int pk = (((unsigned int)hh) << 16) | (unsigned int)hl;
      size_t hoff = (size_t)hkt*512 + hlane*8 + hj;
      hpk[((((size_t)dir*S_ + t)*4 + q) << 13) + hoff] = pk;               // history (plain)
      __hip_atomic_store(hx + ((((size_t)(dir*4 + q))*2 + (ti&1)) << 13) + hoff, pk,
                         __ATOMIC_RELAXED, __HIP_MEMORY_SCOPE_AGENT);      // exchange (atomic)
    }
    // ---- per-wave post: own stores acked (vmcnt 0), then lane0 posts this wave's epoch ----
    asm volatile("s_waitcnt vmcnt(0)" ::: "memory");
    if (lane == 0)
      __hip_atomic_store(dg + g*128 + r*4 + wv, ti + 1, __ATOMIC_RELAXED, __HIP_MEMORY_SCOPE_AGENT);
  }
}

// ---------------- attention scores: one WG per s ----------------
__global__ void __launch_bounds__(256) k_att1(const unsigned int* __restrict__ hpk,
                                              const unsigned short* __restrict__ awhi,
                                              const unsigned short* __restrict__ awlo,
                                              const float* __restrict__ attv,
                                              float* __restrict__ attbuf){
  const int s = blockIdx.x;
  const int tid = threadIdx.x, wv = tid >> 6, lane = tid & 63;
  const int q = wv;
  f32x4 z = {0.f,0.f,0.f,0.f};
  f32x4 acc[4][3];
  #pragma unroll
  for (int nt = 0; nt < 4; ++nt) { acc[nt][0] = z; acc[nt][1] = z; acc[nt][2] = z; }
  for (int kt = 0; kt < 32; ++kt) {
    int dir = kt >> 4, ktt = kt & 15;
    const unsigned int* hb = hpk + ((((size_t)dir*S_ + s)*4 + q) << 13) + ktt*512 + lane*8;
    uint4 u0 = *(const uint4*)hb, u1 = *(const uint4*)(hb + 4);
    bfx8 ah, al; unpack8(u0, u1, ah, al);
    #pragma unroll
    for (int nt = 0; nt < 4; ++nt) {
      bfx8 bh = *(const bfx8*)(awhi + (size_t)((nt*32+kt)*64+lane)*8);
      bfx8 bl = *(const bfx8*)(awlo + (size_t)((nt*32+kt)*64+lane)*8);
      acc[nt][0] = MFMA16(ah, bh, acc[nt][0]);
      acc[nt][1] = MFMA16(ah, bl, acc[nt][1]);
      acc[nt][2] = MFMA16(al, bh, acc[nt][2]);
    }
  }
  float part[4] = {0.f,0.f,0.f,0.f};
  #pragma unroll
  for (int nt = 0; nt < 4; ++nt) {
    f32x4 d = (acc[nt][0] + acc[nt][1]) + acc[nt][2];
    float vvv = attv[nt*16 + (lane&15)];
    #pragma unroll
    for (int rr = 0; rr < 4; ++rr) part[rr] += tanhfast(d[rr]) * vvv;
  }
  #pragma unroll
  for (int m = 1; m < 16; m <<= 1) {
    #pragma unroll
    for (int rr = 0; rr < 4; ++rr) part[rr] += __shfl_xor(part[rr], m, 64);
  }
  if ((lane & 15) == 0) {
    #pragma unroll
    for (int rr = 0; rr < 4; ++rr) {
      int b = q*16 + ((lane>>4)&3)*4 + rr;
      attbuf[(size_t)b*S_ + s] = part[rr];
    }
  }
}

// ---------------- softmax over s per b ----------------
__global__ void __launch_bounds__(256) k_att2(const float* __restrict__ attbuf,
                                              float* __restrict__ wbuf){
  const int b = blockIdx.x, tid = threadIdx.x;
  __shared__ float sm[4];
  float v0 = attbuf[(size_t)b*S_ + tid];
  float v1 = attbuf[(size_t)b*S_ + 256 + tid];
  float m = fmaxf(v0, v1);
  #pragma unroll
  for (int o = 1; o < 64; o <<= 1) m = fmaxf(m, __shfl_xor(m, o, 64));
  if ((tid & 63) == 0) sm[tid >> 6] = m;
  __syncthreads();
  m = fmaxf(fmaxf(sm[0], sm[1]), fmaxf(sm[2], sm[3]));
  __syncthreads();
  float e0 = __expf(v0 - m), e1 = __expf(v1 - m);
  float su = e0 + e1;
  #pragma unroll
  for (int o = 1; o < 64; o <<= 1) su += __shfl_xor(su, o, 64);
  if ((tid & 63) == 0) sm[tid >> 6] = su;
  __syncthreads();
  su = (sm[0] + sm[1]) + (sm[2] + sm[3]);
  wbuf[(size_t)b*S_ + tid]       = e0 / su;
  wbuf[(size_t)b*S_ + 256 + tid] = e1 / su;
}

// ---------------- weighted sum: out[b][2H] ----------------
__global__ void __launch_bounds__(256) k_att3(const unsigned int* __restrict__ hpk,
                                              const float* __restrict__ wbuf,
                                              float* __restrict__ out){
  const int bid = blockIdx.x;              // 128
  const int dir = bid >> 6, q = (bid >> 4) & 3, kt = bid & 15;
  const int tid = threadIdx.x;
  __shared__ float wl[16*512];
  for (int i = tid; i < 16*512; i += 256) {
    int bb = i >> 9, ss = i & 511;
    wl[i] = wbuf[(size_t)(q*16 + bb)*S_ + ss];
  }
  __syncthreads();
  const int l2 = tid >> 2, jj = (tid & 3)*2;
  const int b_l = l2 & 15;
  float acc0 = 0.f, acc1 = 0.f;
  for (int t = 0; t < S_; ++t) {
    const unsigned int* hb = hpk + ((((size_t)dir*S_ + t)*4 + q) << 13) + kt*512 + l2*8 + jj;
    uint2 u = *(const uint2*)hb;
    float w = wl[b_l*512 + t];
    acc0 += w * (bf2f((unsigned short)(u.x >> 16)) + bf2f((unsigned short)(u.x & 0xffffu)));
    acc1 += w * (bf2f((unsigned short)(u.y >> 16)) + bf2f((unsigned short)(u.y & 0xffffu)));
  }
  int k = kt*32 + ((l2 >> 4) & 3)*8 + jj;
  float* o = out + (size_t)(q*16 + b_l)*1024 + dir*512 + k;
  o[0] = acc0;
  o[1] = acc1;
}

// ---------------- launcher ----------------
extern "C" void kernel_launch(void* const* d_in, const int* in_sizes, int n_in,
                              void* d_out, int out_size, void* d_ws, size_t ws_size,
                              hipStream_t stream) {
  const float* x     = (const float*)d_in[0];
  const float* fWih  = (const float*)d_in[1];
  const float* fWhh  = (const float*)d_in[2];
  const float* fbih  = (const float*)d_in[3];
  const float* fbhh  = (const float*)d_in[4];
  const float* bWih  = (const float*)d_in[5];
  const float* bWhh  = (const float*)d_in[6];
  const float* bbih  = (const float*)d_in[7];
  const float* bbhh  = (const float*)d_in[8];
  const float* attW  = (const float*)d_in[9];
  const float* attv  = (const float*)d_in[10];
  float* out = (float*)d_out;

  char* ws = (char*)d_ws;
  const size_t OFF_HPK  = 0;
  const size_t OFF_XHI  = 134217728;            // 128 MB
  const size_t OFF_XLO  = OFF_XHI + 16777216;
  const size_t OFF_WHI  = OFF_XLO + 16777216;   // 160 MB
  const size_t OFF_WLO  = OFF_WHI + 8388608;
  const size_t OFF_AWHI = OFF_WLO + 8388608;    // 176 MB
  const size_t OFF_AWLO = OFF_AWHI + 131072;
  const size_t OFF_ATTB = OFF_AWLO + 131072;
  const size_t OFF_WBUF = OFF_ATTB + 131072;
  const size_t OFF_DG   = OFF_WBUF + 131072;
  const size_t OFF_HX   = OFF_DG + 4096;        // 512 KB rotating exchange

  unsigned int*   hpk  = (unsigned int*)(ws + OFF_HPK);
  unsigned short* xhi  = (unsigned short*)(ws + OFF_XHI);
  unsigned short* xlo  = (unsigned short*)(ws + OFF_XLO);
  unsigned short* whi  = (unsigned short*)(ws + OFF_WHI);
  unsigned short* wlo  = (unsigned short*)(ws + OFF_WLO);
  unsigned short* awhi = (unsigned short*)(ws + OFF_AWHI);
  unsigned short* awlo = (unsigned short*)(ws + OFF_AWLO);
  float*          attb = (float*)(ws + OFF_ATTB);
  float*          wbuf = (float*)(ws + OFF_WBUF);
  int*            dg   = (int*)(ws + OFF_DG);
  unsigned int*   hx   = (unsigned int*)(ws + OFF_HX);

  // zero the epoch digests (128 wave-words x 8 groups = 4 KB)
  hipMemsetAsync(dg, 0, 4096, stream);

  k_xfrag <<<4096, 256, 0, stream>>>(x, xhi, xlo);
  k_wfrag <<<2048, 256, 0, stream>>>(fWih, bWih, whi, wlo);
  k_awfrag<<<32,   256, 0, stream>>>(attW, awhi, awlo);

  const int LDS_BYTES = 151552;   // 80K Whh + 32K h-stage + 4K gbuf + 32K xbuf
  hipFuncSetAttribute((const void*)k_lstm, hipFuncAttributeMaxDynamicSharedMemorySize, LDS_BYTES);
  k_lstm<<<256, 256, LDS_BYTES, stream>>>(fWhh, bWhh, fbih, fbhh, bbih, bbhh,
                                          hpk, hx, xhi, xlo, whi, wlo, dg);

  k_att1<<<512, 256, 0, stream>>>(hpk, awhi, awlo, attv, attb);
  k_att2<<<64,  256, 0, stream>>>(attb, wbuf);
  k_att3<<<128, 256, 0, stream>>>(hpk, wbuf, out);
}